// Round 2
// baseline (403.240 us; speedup 1.0000x reference)
//
#include <hip/hip_runtime.h>
#include <math.h>

// Problem: B=4, S=4096, D=2048, E=64, TOP_K=2
#define M_TOK 16384
#define D_DIM 2048
#define E_EXP 64
#define BM 64          // tokens per block
#define BK 32          // K-tile
#define AS_LD 66       // doubles; As[k][token], token dim padded 64->66
#define W_GRP 10       // 8 cols + 2 pad doubles; bank(20g % 32) distinct for g=0..7 -> conflict-free
#define W_LD  80       // 8 groups * 10 doubles per k-row

// LDS doubles: As 32*66=2112, Wr 32*80=2560, Wn 2560  -> 7232 doubles = 57,856 B
#define SMEM_DOUBLES (BK*AS_LD + 2*BK*W_LD)

__device__ __forceinline__ bool beats(double va, int ia, double vb, int ib) {
    // jax.lax.top_k order: larger value first; ties -> lower index first
    return (va > vb) || (va == vb && ia < ib);
}

__global__ __launch_bounds__(256) void noisy_topk_router_kernel(
    const float* __restrict__ A,      // [M, D] mh_output
    const float* __restrict__ Wr,     // [D, E]
    const float* __restrict__ br,     // [E]
    const float* __restrict__ Wn,     // [D, E]
    const float* __restrict__ bn,     // [E]
    const float* __restrict__ noise,  // [M, E]
    float* __restrict__ probs,        // [M, E]   float32
    float* __restrict__ idx_out)      // [M, 2]   indices as float
{
    __shared__ __align__(16) double smem[SMEM_DOUBLES];
    double* Asd = smem;                 // [BK][AS_LD]  A transposed: Asd[k][token]
    double* Wsr = smem + BK * AS_LD;    // [BK][W_LD]   grouped/padded
    double* Wsn = Wsr + BK * W_LD;

    const int tid = threadIdx.x;
    const int tx  = tid & 15;           // 0..7 route cols, 8..15 noise cols
    const int ty  = tid >> 4;           // token group (4 tokens each)
    const int grp = tx & 7;             // column group: cols grp*8 .. grp*8+7
    const bool isNoise = (tx >= 8);
    const int tokBase = blockIdx.x * BM;

    double acc[4][8];
    #pragma unroll
    for (int r = 0; r < 4; ++r)
        #pragma unroll
        for (int c = 0; c < 8; ++c) acc[r][c] = 0.0;

    // ---- staging mapping ----
    const int a_kq  = tid & 7;          // which float4 in K-tile
    const int a_tok = tid >> 3;         // 0..31 (handles tokens a_tok, a_tok+32)
    const float* Ag0 = A + (size_t)(tokBase + a_tok) * D_DIM + a_kq * 4;
    const float* Ag1 = Ag0 + (size_t)32 * D_DIM;
    // W slab element base for this thread: k-row wk, col we (and wk+16 for 2nd half)
    const int wk = tid >> 4;            // 0..15
    const int we = (tid * 4) & 63;      // 0,4,..,60
    const int wofs = (we >> 3) * W_GRP + (we & 7);   // grouped LDS offset within k-row

    float4 pa0, pa1, pwr0, pwr1, pwn0, pwn1;
    // prefetch tile 0
    pa0 = *(const float4*)(Ag0);
    pa1 = *(const float4*)(Ag1);
    pwr0 = *(const float4*)(Wr + tid * 4);
    pwr1 = *(const float4*)(Wr + 1024 + tid * 4);
    pwn0 = *(const float4*)(Wn + tid * 4);
    pwn1 = *(const float4*)(Wn + 1024 + tid * 4);

    const int NKT = D_DIM / BK;         // 64 tiles
    for (int kt = 0; kt < NKT; ++kt) {
        // regs -> LDS (convert to double here: 24 cvts/tile/thread)
        {
            const int kb = a_kq * 4;
            Asd[(kb + 0) * AS_LD + a_tok]      = (double)pa0.x;
            Asd[(kb + 1) * AS_LD + a_tok]      = (double)pa0.y;
            Asd[(kb + 2) * AS_LD + a_tok]      = (double)pa0.z;
            Asd[(kb + 3) * AS_LD + a_tok]      = (double)pa0.w;
            Asd[(kb + 0) * AS_LD + a_tok + 32] = (double)pa1.x;
            Asd[(kb + 1) * AS_LD + a_tok + 32] = (double)pa1.y;
            Asd[(kb + 2) * AS_LD + a_tok + 32] = (double)pa1.z;
            Asd[(kb + 3) * AS_LD + a_tok + 32] = (double)pa1.w;
            double* wr0 = Wsr + wk * W_LD + wofs;
            double* wr1 = Wsr + (wk + 16) * W_LD + wofs;
            wr0[0] = (double)pwr0.x; wr0[1] = (double)pwr0.y;
            wr0[2] = (double)pwr0.z; wr0[3] = (double)pwr0.w;
            wr1[0] = (double)pwr1.x; wr1[1] = (double)pwr1.y;
            wr1[2] = (double)pwr1.z; wr1[3] = (double)pwr1.w;
            double* wn0 = Wsn + wk * W_LD + wofs;
            double* wn1 = Wsn + (wk + 16) * W_LD + wofs;
            wn0[0] = (double)pwn0.x; wn0[1] = (double)pwn0.y;
            wn0[2] = (double)pwn0.z; wn0[3] = (double)pwn0.w;
            wn1[0] = (double)pwn1.x; wn1[1] = (double)pwn1.y;
            wn1[2] = (double)pwn1.z; wn1[3] = (double)pwn1.w;
        }
        __syncthreads();

        // prefetch next tile while computing this one
        if (kt + 1 < NKT) {
            const int k0 = (kt + 1) * BK;
            pa0 = *(const float4*)(Ag0 + k0);
            pa1 = *(const float4*)(Ag1 + k0);
            const float* wr = Wr + (size_t)k0 * 64;
            const float* wn = Wn + (size_t)k0 * 64;
            pwr0 = *(const float4*)(wr + tid * 4);
            pwr1 = *(const float4*)(wr + 1024 + tid * 4);
            pwn0 = *(const float4*)(wn + tid * 4);
            pwn1 = *(const float4*)(wn + 1024 + tid * 4);
        }

        const double* Wuse = isNoise ? Wsn : Wsr;
        const double* wrow = Wuse + grp * W_GRP;
        #pragma unroll 4
        for (int k = 0; k < BK; ++k) {
            const double* ar = Asd + k * AS_LD + ty * 4;   // 16-lane broadcast, conflict-free
            const double* wp = wrow + k * W_LD;            // 8-lane broadcast, conflict-free
            double av[4], wv[8];
            #pragma unroll
            for (int r = 0; r < 4; ++r) av[r] = ar[r];
            #pragma unroll
            for (int c = 0; c < 8; ++c) wv[c] = wp[c];
            #pragma unroll
            for (int r = 0; r < 4; ++r)
                #pragma unroll
                for (int c = 0; c < 8; ++c)
                    acc[r][c] = fma(av[r], wv[c], acc[r][c]);
        }
        __syncthreads();
    }

    // ---- epilogue ----
    // cooperative zero of this block's probs slab (64 tok * 64 exp), then barrier
    float* pbase = probs + (size_t)tokBase * E_EXP;
    {
        const float4 z = make_float4(0.f, 0.f, 0.f, 0.f);
        #pragma unroll
        for (int j = 0; j < 4; ++j)
            *(float4*)(pbase + (size_t)(j * 256 + tid) * 4) = z;
    }
    __syncthreads();

    // biases for my 8 cols (b_route/b_noise are zeros in setup, but be general)
    double brv[8], bnv[8];
    {
        const float4 b0 = *(const float4*)(br + grp * 8);
        const float4 b1 = *(const float4*)(br + grp * 8 + 4);
        const float4 c0 = *(const float4*)(bn + grp * 8);
        const float4 c1 = *(const float4*)(bn + grp * 8 + 4);
        brv[0]=b0.x; brv[1]=b0.y; brv[2]=b0.z; brv[3]=b0.w;
        brv[4]=b1.x; brv[5]=b1.y; brv[6]=b1.z; brv[7]=b1.w;
        bnv[0]=c0.x; bnv[1]=c0.y; bnv[2]=c0.z; bnv[3]=c0.w;
        bnv[4]=c1.x; bnv[5]=c1.y; bnv[6]=c1.z; bnv[7]=c1.w;
    }

    // For each of my 4 tokens: route lanes (tx<8) pull noise-logit accs from lane+8,
    // compute noisy logits in f64, local top-2 over 8 cols, butterfly-merge over 8 lanes.
    // ALL threads execute the shuffles (tx>=8 results are garbage and unused).
    #pragma unroll
    for (int r = 0; r < 4; ++r) {
        const int t = ty * 4 + r;
        const float* nz = noise + (size_t)(tokBase + t) * E_EXP + grp * 8;
        const float4 n0 = *(const float4*)(nz);
        const float4 n1 = *(const float4*)(nz + 4);
        const float nv[8] = {n0.x, n0.y, n0.z, n0.w, n1.x, n1.y, n1.z, n1.w};

        double v0 = -INFINITY, v1 = -INFINITY;
        int i0 = 0, i1 = 0;
        #pragma unroll
        for (int c = 0; c < 8; ++c) {
            const double ln = __shfl_down(acc[r][c], 8) + bnv[c];   // noise logit (valid for tx<8)
            const double lr = acc[r][c] + brv[c];                   // route logit
            const double sp = fmax(ln, 0.0) + log1p(exp(-fabs(ln))); // softplus, f64
            const double v  = fma((double)nv[c], sp, lr);
            const int e = grp * 8 + c;
            if (beats(v, e, v0, i0)) { v1 = v0; i1 = i0; v0 = v; i0 = e; }
            else if (beats(v, e, v1, i1)) { v1 = v; i1 = e; }
        }
        // butterfly merge across the 8 route lanes (same ty, tx 0..7; xor stays in-wave)
        #pragma unroll
        for (int m = 1; m < 8; m <<= 1) {
            const double w0 = __shfl_xor(v0, m), w1 = __shfl_xor(v1, m);
            const int    j0 = __shfl_xor(i0, m), j1 = __shfl_xor(i1, m);
            if (beats(v0, i0, w0, j0)) {
                if (!beats(v1, i1, w0, j0)) { v1 = w0; i1 = j0; }
            } else {
                if (beats(v0, i0, w1, j1)) { v1 = v0; i1 = i0; }
                else                       { v1 = w1; i1 = j1; }
                v0 = w0; i0 = j0;
            }
        }
        if (tx == r) {   // one writer per token
            const double e1 = exp(v1 - v0);        // <= 1
            const double den = 1.0 + e1;
            pbase[t * E_EXP + i0] = (float)(1.0 / den);
            pbase[t * E_EXP + i1] = (float)(e1 / den);
            const size_t ib = (size_t)(tokBase + t) * 2;
            idx_out[ib]     = (float)i0;
            idx_out[ib + 1] = (float)i1;
        }
    }
}

extern "C" void kernel_launch(void* const* d_in, const int* in_sizes, int n_in,
                              void* d_out, int out_size, void* d_ws, size_t ws_size,
                              hipStream_t stream) {
    (void)in_sizes; (void)n_in; (void)out_size; (void)d_ws; (void)ws_size;
    const float* A  = (const float*)d_in[0];   // mh_output [4,4096,2048]
    const float* Wr = (const float*)d_in[1];   // W_route   [2048,64]
    const float* br = (const float*)d_in[2];   // b_route   [64]
    const float* Wn = (const float*)d_in[3];   // W_noise   [2048,64]
    const float* bn = (const float*)d_in[4];   // b_noise   [64]
    const float* nz = (const float*)d_in[5];   // noise     [4,4096,64]

    float* probs = (float*)d_out;                    // [4,4096,64] float32
    float* idxo  = probs + (size_t)M_TOK * E_EXP;    // [4,4096,2] as float

    noisy_topk_router_kernel<<<M_TOK / BM, 256, 0, stream>>>(A, Wr, br, Wn, bn, nz, probs, idxo);
}

// Round 3
// 372.219 us; speedup vs baseline: 1.0833x; 1.0833x over previous
//
#include <hip/hip_runtime.h>
#include <math.h>

// Problem: B=4, S=4096, D=2048, E=64, TOP_K=2
#define M_TOK 16384
#define D_DIM 2048
#define E_EXP 64
#define BM 64          // tokens per gemm block
#define BK 16          // K-tile
#define AS_LD 66       // doubles; As[k][token], 64 tokens + 2 pad
#define W_GRP 10       // 8 cols + 2 pad doubles per chunk -> chunk start banks 20c%32 all distinct
#define W_LD  82       // 8 chunks*10 + 2 row pad; 82*2%32=4 so k-rows spread store banks

// per-kc partial-logit slab: [M_TOK][128] f64 (cols 0..63 route, 64..127 noise)
#define SLAB_ELEMS ((size_t)M_TOK * 128)
#define SLAB_BYTES (SLAB_ELEMS * 8)

// LDS doubles: As 16*66=1056, W 2*16*82=2624  -> 3680 dbl = 29,440 B -> 5 blocks/CU LDS-wise
#define SMEM_DOUBLES (BK * AS_LD + 2 * BK * W_LD)

__device__ __forceinline__ bool beats(double va, int ia, double vb, int ib) {
    // jax.lax.top_k order: larger value first; ties -> lower index first
    return (va > vb) || (va == vb && ia < ib);
}

// ---------------- stage 1: K-split partial GEMM (f64 accumulate) ----------------
__global__ __launch_bounds__(256, 4) void gemm_partial_kernel(
    const float* __restrict__ A,      // [M, D]
    const float* __restrict__ Wr,     // [D, E]
    const float* __restrict__ Wn,     // [D, E]
    double* __restrict__ ws,          // [kc][M][128] f64 partials
    int klen)                         // K elements per kc chunk
{
    __shared__ __align__(16) double smem[SMEM_DOUBLES];
    double* Asd = smem;                 // [BK][AS_LD]  A transposed: Asd[k][token]
    double* Wsr = smem + BK * AS_LD;    // [BK][W_LD]   grouped
    double* Wsn = Wsr + BK * W_LD;

    const int tid  = threadIdx.x;
    const int tile = blockIdx.x & 255;  // token tile 0..255
    const int kc   = blockIdx.x >> 8;   // K chunk
    const int k0   = kc * klen;
    const int tokBase = tile * BM;

    const int tx  = tid & 15;           // 0..7 route col-groups, 8..15 noise
    const int ty  = tid >> 4;           // token group (4 tokens each)
    const int grp = tx & 7;
    const bool isNoise = (tx >= 8);

    double acc[4][8];
    #pragma unroll
    for (int r = 0; r < 4; ++r)
        #pragma unroll
        for (int c = 0; c < 8; ++c) acc[r][c] = 0.0;

    // staging mapping: A: 64 tok x 4 float4 -> 1 float4/thread
    const int a_kq  = tid & 3;          // which float4 in the 16-wide K-tile
    const int a_tok = tid >> 2;         // 0..63
    const float* Ag = A + (size_t)(tokBase + a_tok) * D_DIM + k0 + a_kq * 4;
    // W: 16 rows x 16 float4 -> 1 float4/thread per matrix
    const int wk  = tid >> 4;           // k row 0..15
    const int wc4 = (tid & 15) * 4;     // col 0,4,...,60
    const float* Wrg = Wr + (size_t)(k0 + wk) * E_EXP + wc4;
    const float* Wng = Wn + (size_t)(k0 + wk) * E_EXP + wc4;
    const int wofs = wk * W_LD + (wc4 >> 3) * W_GRP + (wc4 & 7);  // 16B-aligned

    float4 pa, pwr, pwn;
    pa  = *(const float4*)(Ag);
    pwr = *(const float4*)(Wrg);
    pwn = *(const float4*)(Wng);

    const int NT = klen / BK;
    for (int kt = 0; kt < NT; ++kt) {
        // regs -> LDS (f32 -> f64 conversion here)
        {
            const int kb = a_kq * 4;
            Asd[(kb + 0) * AS_LD + a_tok] = (double)pa.x;   // 2-way store conflicts only (free)
            Asd[(kb + 1) * AS_LD + a_tok] = (double)pa.y;
            Asd[(kb + 2) * AS_LD + a_tok] = (double)pa.z;
            Asd[(kb + 3) * AS_LD + a_tok] = (double)pa.w;
            double* wr = Wsr + wofs;
            wr[0] = (double)pwr.x; wr[1] = (double)pwr.y;
            wr[2] = (double)pwr.z; wr[3] = (double)pwr.w;
            double* wn = Wsn + wofs;
            wn[0] = (double)pwn.x; wn[1] = (double)pwn.y;
            wn[2] = (double)pwn.z; wn[3] = (double)pwn.w;
        }
        __syncthreads();

        // prefetch next tile while computing this one
        if (kt + 1 < NT) {
            const int ko = (kt + 1) * BK;
            pa  = *(const float4*)(Ag + ko);
            pwr = *(const float4*)(Wrg + (size_t)ko * E_EXP);
            pwn = *(const float4*)(Wng + (size_t)ko * E_EXP);
        }

        const double* Wuse = (isNoise ? Wsn : Wsr) + grp * W_GRP;
        #pragma unroll 4
        for (int k = 0; k < BK; ++k) {
            const double* ar = Asd + k * AS_LD + ty * 4;   // 16-lane broadcast
            const double* wp = Wuse + k * W_LD;            // chunk starts on distinct banks
            double av[4], wv[8];
            #pragma unroll
            for (int r = 0; r < 4; ++r) av[r] = ar[r];
            #pragma unroll
            for (int c = 0; c < 8; ++c) wv[c] = wp[c];
            #pragma unroll
            for (int r = 0; r < 4; ++r)
                #pragma unroll
                for (int c = 0; c < 8; ++c)
                    acc[r][c] = fma(av[r], wv[c], acc[r][c]);
        }
        __syncthreads();
    }

    // write partials: 8 contiguous doubles per (thread, token); 16 tx-threads of a
    // token cover 1 KB contiguous -> coalesced
    #pragma unroll
    for (int r = 0; r < 4; ++r) {
        const int t = ty * 4 + r;
        double* dst = ws + (size_t)kc * SLAB_ELEMS
                         + ((size_t)(tokBase + t)) * 128 + (isNoise ? 64 : 0) + grp * 8;
        #pragma unroll
        for (int c = 0; c < 4; ++c)
            *(double2*)(dst + 2 * c) = make_double2(acc[r][2 * c], acc[r][2 * c + 1]);
    }
}

// ---------------- stage 2: sum partials + softplus + top-2 + softmax ----------------
__global__ __launch_bounds__(256) void epilogue_kernel(
    const double* __restrict__ ws,    // [kcc][M][128]
    const float* __restrict__ br,
    const float* __restrict__ bn,
    const float* __restrict__ noise,  // [M, E]
    float* __restrict__ probs,        // [M, E]
    float* __restrict__ idx_out,      // [M, 2] as float
    int kcc)
{
    const int tid = threadIdx.x;
    const int tokBase = blockIdx.x * 64;

    // cooperative zero of this block's probs slab (64 tok * 64 exp = 4096 floats)
    float* pb0 = probs + (size_t)tokBase * E_EXP;
    {
        const float4 z = make_float4(0.f, 0.f, 0.f, 0.f);
        #pragma unroll
        for (int j = 0; j < 4; ++j)
            *(float4*)(pb0 + (size_t)(j * 256 + tid) * 4) = z;
    }
    __syncthreads();

    const int t_loc = tid >> 2;         // token within block (0..63)
    const int s     = tid & 3;          // col quarter: cols s*16 .. s*16+15
    const int token = tokBase + t_loc;

    // sum kcc partial slabs (f64, exact to ~1e-16)
    double lr[16], ln[16];
    {
        const double* p = ws + (size_t)token * 128 + s * 16;
        #pragma unroll
        for (int j = 0; j < 8; ++j) {
            double2 a = *(const double2*)(p + 2 * j);
            lr[2 * j] = a.x; lr[2 * j + 1] = a.y;
            double2 b = *(const double2*)(p + 64 + 2 * j);
            ln[2 * j] = b.x; ln[2 * j + 1] = b.y;
        }
        for (int c = 1; c < kcc; ++c) {
            const double* q = p + (size_t)c * SLAB_ELEMS;
            #pragma unroll
            for (int j = 0; j < 8; ++j) {
                double2 a = *(const double2*)(q + 2 * j);
                lr[2 * j] += a.x; lr[2 * j + 1] += a.y;
                double2 b = *(const double2*)(q + 64 + 2 * j);
                ln[2 * j] += b.x; ln[2 * j + 1] += b.y;
            }
        }
    }

    // noisy logits (f64), local top-2 over my 16 cols
    double v0 = -INFINITY, v1 = -INFINITY;
    int i0 = 0, i1 = 0;
    {
        const float* nz = noise + (size_t)token * E_EXP + s * 16;
        #pragma unroll
        for (int q = 0; q < 4; ++q) {
            const float4 n4 = *(const float4*)(nz + q * 4);
            const float4 b4 = *(const float4*)(br + s * 16 + q * 4);
            const float4 c4 = *(const float4*)(bn + s * 16 + q * 4);
            const float nv[4] = {n4.x, n4.y, n4.z, n4.w};
            const float bv[4] = {b4.x, b4.y, b4.z, b4.w};
            const float cv[4] = {c4.x, c4.y, c4.z, c4.w};
            #pragma unroll
            for (int j = 0; j < 4; ++j) {
                const int cc = q * 4 + j;
                const double lnn = ln[cc] + (double)cv[j];
                const double sp  = fmax(lnn, 0.0) + log1p(exp(-fabs(lnn)));   // softplus
                const double v   = fma((double)nv[j], sp, lr[cc] + (double)bv[j]);
                const int e = s * 16 + cc;
                if (beats(v, e, v0, i0)) { v1 = v0; i1 = i0; v0 = v; i0 = e; }
                else if (beats(v, e, v1, i1)) { v1 = v; i1 = e; }
            }
        }
    }

    // merge across the 4 lanes of this token (masks 1,2 stay within the aligned quad)
    #pragma unroll
    for (int m = 1; m < 4; m <<= 1) {
        const double w0 = __shfl_xor(v0, m), w1 = __shfl_xor(v1, m);
        const int    j0 = __shfl_xor(i0, m), j1 = __shfl_xor(i1, m);
        if (beats(v0, i0, w0, j0)) {
            if (!beats(v1, i1, w0, j0)) { v1 = w0; i1 = j0; }
        } else {
            if (beats(v0, i0, w1, j1)) { v1 = v0; i1 = i0; }
            else                       { v1 = w1; i1 = j1; }
            v0 = w0; i0 = j0;
        }
    }

    if (s == 0) {
        const double e1  = exp(v1 - v0);     // <= 1
        const double den = 1.0 + e1;
        float* pb = probs + (size_t)token * E_EXP;
        pb[i0] = (float)(1.0 / den);
        pb[i1] = (float)(e1 / den);
        *(float2*)(idx_out + (size_t)token * 2) = make_float2((float)i0, (float)i1);
    }
}

extern "C" void kernel_launch(void* const* d_in, const int* in_sizes, int n_in,
                              void* d_out, int out_size, void* d_ws, size_t ws_size,
                              hipStream_t stream) {
    (void)in_sizes; (void)n_in; (void)out_size;
    const float* A  = (const float*)d_in[0];   // mh_output [4,4096,2048]
    const float* Wr = (const float*)d_in[1];   // W_route   [2048,64]
    const float* br = (const float*)d_in[2];   // b_route   [64]
    const float* Wn = (const float*)d_in[3];   // W_noise   [2048,64]
    const float* bn = (const float*)d_in[4];   // b_noise   [64]
    const float* nz = (const float*)d_in[5];   // noise     [4,4096,64]

    float* probs = (float*)d_out;                    // [4,4096,64] float32
    float* idxo  = probs + (size_t)M_TOK * E_EXP;    // [4,4096,2] as float

    // K-split factor limited by workspace (each chunk needs a 16.8 MB f64 slab)
    int kcc = 1;
    if (ws_size >= 4 * SLAB_BYTES)      kcc = 4;
    else if (ws_size >= 2 * SLAB_BYTES) kcc = 2;

    gemm_partial_kernel<<<256 * kcc, 256, 0, stream>>>(A, Wr, Wn, (double*)d_ws, D_DIM / kcc);
    epilogue_kernel<<<M_TOK / 64, 256, 0, stream>>>((const double*)d_ws, br, bn, nz,
                                                    probs, idxo, kcc);
}